// Round 1
// baseline (623.922 us; speedup 1.0000x reference)
//
#include <hip/hip_runtime.h>
#include <math.h>

#define B_   8
#define T_   2048
#define J_   17
#define D_   129
#define d_   128
#define H_   8
#define BJ_  (B_ * J_)      // 136
#define EPS_ 1e-6f

// pass_kv: 8 chunks (fewer global atomics), pass_out: 16 (finer tail at 4 blk/CU)
#define CHK  8
#define RPBK (T_ / CHK)     // 256 rows per block
#define NITK (RPBK / 64)    // 4
#define CHO  16
#define RPBO (T_ / CHO)     // 128 rows per block
#define NITO (RPBO / 64)    // 2

typedef short bf8 __attribute__((ext_vector_type(8)));   // 8 bf16 in 4 VGPRs
typedef float fx4 __attribute__((ext_vector_type(4)));

__device__ __forceinline__ float phi_f(float x) {
    return x > 0.f ? x + 1.f : __expf(x);
}
__device__ __forceinline__ short f2b(float f) {            // fp32->bf16 RNE
    union { float f; unsigned u; } c; c.f = f;
    unsigned u = c.u + 0x7fffu + ((c.u >> 16) & 1u);
    return (short)(u >> 16);
}
__device__ __forceinline__ float b2f(short s) {
    union { float f; unsigned u; } c;
    c.u = ((unsigned)(unsigned short)s) << 16;
    return c.f;
}
// 8 consecutive floats -> bf16 fragment via two float4 loads (16B aligned).
__device__ __forceinline__ bf8 ld_w8(const float* p) {
    const float4* q = reinterpret_cast<const float4*>(p);
    float4 a = q[0], b = q[1];
    bf8 t;
    t[0] = f2b(a.x); t[1] = f2b(a.y); t[2] = f2b(a.z); t[3] = f2b(a.w);
    t[4] = f2b(b.x); t[5] = f2b(b.y); t[6] = f2b(b.z); t[7] = f2b(b.w);
    return t;
}

// ============================================================================
// Pass A: k/v GEMM (cols 128..383 of qkv) + kv[h] += k_m^T v + ksum, per bj.
// Grid (CHK, BJ), block 256 (4 waves). Wave w computes output cols 64w..64w+63.
// nt processed in 2 pairs (acc[2][4]) to keep VGPR <= 170 -> 3 blocks/CU.
// 2 barriers/iter: stage->GEMM (cross-wave sx), epilogue->kvMFMA (cross-wave kT/vT).
// ============================================================================
__global__ __launch_bounds__(256, 3) void pass_kv(
        const float* __restrict__ x, const float* __restrict__ wqkv,
        const float* __restrict__ bqkv,
        float* __restrict__ kvw,       // [BJ][H][16(j=v-feat)][16(i=k-feat)]
        float* __restrict__ ksw) {     // [BJ][128]
    const int bj = blockIdx.y, b = bj / J_, j = bj % J_;
    const int t0 = blockIdx.x * RPBK;
    const int tid = threadIdx.x, wave = tid >> 6, lane = tid & 63;
    const int quad = lane >> 4, l16 = lane & 15;

    __shared__ __align__(16) short sx[64 * 136];     // x tile, bf16 (17408 B)
    __shared__ __align__(16) short kT[128 * 72];     // k_m^T : [feat][t], 16B rows
    __shared__ __align__(16) short vT[128 * 72];     // v^T       (total 54272 B)

    // Register-resident B fragments: B[k][n] = W[n][k], n = 128 + 64w+16nt+l16
    bf8 wf[4][4];
    float bias[4];
    #pragma unroll
    for (int nt = 0; nt < 4; ++nt) {
        const int n = d_ + wave * 64 + nt * 16 + l16;
        bias[nt] = bqkv[n];
        #pragma unroll
        for (int ks = 0; ks < 4; ++ks)
            wf[nt][ks] = ld_w8(wqkv + (size_t)n * d_ + ks * 32 + quad * 8);
    }

    fx4 kva[2];
    kva[0] = (fx4){0.f, 0.f, 0.f, 0.f};
    kva[1] = (fx4){0.f, 0.f, 0.f, 0.f};
    float ksp[4] = {0.f, 0.f, 0.f, 0.f};

    for (int it = 0; it < NITK; ++it) {
        {   // stage x tile -> bf16 LDS (sx disjoint from kT/vT: no top barrier)
            const int tb = t0 + it * 64;
            #pragma unroll
            for (int i = 0; i < 16; ++i) {
                const int F = tid + 256 * i, row = F >> 6, c2 = F & 63;
                const float* xr = x + ((size_t)((b * T_ + tb + row) * J_ + j)) * D_ + 1 + 2 * c2;
                *reinterpret_cast<unsigned*>(&sx[row * 136 + 2 * c2]) =
                    (unsigned)(unsigned short)f2b(xr[0]) |
                    ((unsigned)(unsigned short)f2b(xr[1]) << 16);
            }
        }
        __syncthreads();   // sx ready; also orders prev-iter kvMFMA reads vs kT/vT writes below

        short* dst = (wave < 2) ? kT : vT;
        const int fbase = (wave & 1) * 64;
        const bool isk = (wave < 2);

        #pragma unroll
        for (int pr = 0; pr < 2; ++pr) {           // nt pair {2pr, 2pr+1}
            fx4 acc[2][4];
            #pragma unroll
            for (int n2 = 0; n2 < 2; ++n2)
                #pragma unroll
                for (int mt = 0; mt < 4; ++mt) acc[n2][mt] = (fx4){0.f, 0.f, 0.f, 0.f};

            #pragma unroll
            for (int ks = 0; ks < 4; ++ks) {
                bf8 af[4];
                #pragma unroll
                for (int mt = 0; mt < 4; ++mt)
                    af[mt] = *reinterpret_cast<const bf8*>(
                        &sx[(mt * 16 + l16) * 136 + ks * 32 + quad * 8]);
                #pragma unroll
                for (int n2 = 0; n2 < 2; ++n2)
                    #pragma unroll
                    for (int mt = 0; mt < 4; ++mt)
                        acc[n2][mt] = __builtin_amdgcn_mfma_f32_16x16x32_bf16(
                            af[mt], wf[pr * 2 + n2][ks], acc[n2][mt], 0, 0, 0);
            }

            // epilogue: bias (+phi for k), transpose-write to kT / vT
            #pragma unroll
            for (int n2 = 0; n2 < 2; ++n2) {
                const int nt = pr * 2 + n2;
                #pragma unroll
                for (int mt = 0; mt < 4; ++mt) {
                    unsigned long long pk = 0ull;
                    #pragma unroll
                    for (int r = 0; r < 4; ++r) {
                        float v = acc[n2][mt][r] + bias[nt];
                        if (isk) { v = phi_f(v); ksp[nt] += v; }
                        pk |= ((unsigned long long)(unsigned short)f2b(v)) << (16 * r);
                    }
                    *reinterpret_cast<unsigned long long*>(
                        &dst[(fbase + nt * 16 + l16) * 72 + mt * 16 + quad * 4]) = pk;
                }
            }
        }
        __syncthreads();   // kT/vT ready (cross-wave)

        // kv[h] += k_m^T(16 x 64t) * v(64t x 16): K = t, two 32-steps
        #pragma unroll
        for (int hh = 0; hh < 2; ++hh) {
            const int h = wave * 2 + hh;
            #pragma unroll
            for (int ks2 = 0; ks2 < 2; ++ks2) {
                bf8 ak = *reinterpret_cast<const bf8*>(
                    &kT[(h * 16 + l16) * 72 + ks2 * 32 + quad * 8]);
                bf8 bv = *reinterpret_cast<const bf8*>(
                    &vT[(h * 16 + l16) * 72 + ks2 * 32 + quad * 8]);
                kva[hh] = __builtin_amdgcn_mfma_f32_16x16x32_bf16(ak, bv, kva[hh], 0, 0, 0);
            }
        }
    }

    // commit: kv C layout col=l16=j(v-feat), row=quad*4+r=i(k-feat)
    #pragma unroll
    for (int hh = 0; hh < 2; ++hh) {
        const int h = wave * 2 + hh;
        float* p = kvw + (((size_t)bj * H_ + h) * 16 + l16) * 16 + quad * 4;
        #pragma unroll
        for (int r = 0; r < 4; ++r) atomicAdd(p + r, kva[hh][r]);
    }
    if (wave < 2) {
        #pragma unroll
        for (int nt = 0; nt < 4; ++nt) {
            float s = ksp[nt];
            s += __shfl_xor(s, 16);
            s += __shfl_xor(s, 32);
            if (lane < 16)
                atomicAdd(ksw + (size_t)bj * d_ + wave * 64 + nt * 16 + l16, s);
        }
    }
}

// ============================================================================
// Pass B: q GEMM -> phi -> [agg + denominator both via MFMA] -> out GEMM -> store.
// Denominator trick: B-fragment holding ksum replicated over all 16 cols gives
// D[m][n] = sum_k qm[m][k]*ksum[k] for every n -> each lane gets its row's denom
// in exactly the C-layout slot where it scales agg. ksum split hi+lo bf16 keeps
// fp32 accuracy. agg is written IN PLACE over qm (per-wave column stripe; reads
// precede writes by register data-dependence; hh=0 writes disjoint from hh=1 reads).
// 3 barriers/iter. LDS 38.8 KiB -> 4 blocks/CU.
// ============================================================================
__global__ __launch_bounds__(256, 4) void pass_out(
        const float* __restrict__ x, const float* __restrict__ wqkv,
        const float* __restrict__ bqkv, const float* __restrict__ wout,
        const float* __restrict__ bout,
        const float* __restrict__ kvw, const float* __restrict__ ksw,
        float* __restrict__ out) {
    const int bj = blockIdx.y, b = bj / J_, j = bj % J_;
    const int t0 = blockIdx.x * RPBO;
    const int tid = threadIdx.x, wave = tid >> 6, lane = tid & 63;
    const int quad = lane >> 4, l16 = lane & 15;

    __shared__ __align__(16) short sxg[64 * 136];        // x tile (17408 B)
    __shared__ __align__(16) short qm[64 * 136];         // q_m, then agg in-place
    __shared__ __align__(16) short kvT2[H_ * 2 * 16 * 8];// [h][qd][jv][8] (4096 B)
    __shared__ __align__(16) short ksshi[d_];            // ksum hi bf16
    __shared__ __align__(16) short ksslo[d_];            // ksum residual bf16
    __shared__ float rnorm[64];

    bf8 wqf[2][4], wof[2][4];
    float bq2[2], bo2[2];
    #pragma unroll
    for (int nt = 0; nt < 2; ++nt) {
        const int n = wave * 32 + nt * 16 + l16;
        bq2[nt] = bqkv[n];
        bo2[nt] = bout[n];
        #pragma unroll
        for (int ks = 0; ks < 4; ++ks) {
            wqf[nt][ks] = ld_w8(wqkv + (size_t)n * d_ + ks * 32 + quad * 8);
            wof[nt][ks] = ld_w8(wout + (size_t)n * d_ + ks * 32 + quad * 8);
        }
    }
    // stage kv as [h][qd][jv][8] so bk loads are 16B-aligned b128, 2-way max
    #pragma unroll
    for (int u = 0; u < 8; ++u) {
        const int lin = tid + 256 * u;                   // 0..2047
        const int jj = lin & 7, jv = (lin >> 3) & 15, qd = (lin >> 7) & 1, h = lin >> 8;
        kvT2[lin] = f2b(kvw[(((size_t)bj * H_ + h) * 16 + jv) * 16 + qd * 8 + jj]);
    }
    if (tid < d_) {                                      // ksum hi/lo split
        const float v = ksw[(size_t)bj * d_ + tid];
        const short hi = f2b(v);
        ksshi[tid] = hi;
        ksslo[tid] = f2b(v - b2f(hi));
    }
    if (tid < 64) rnorm[tid] = 0.f;

    for (int it = 0; it < NITO; ++it) {
        const int tb = t0 + it * 64;
        {   // stage x tile
            #pragma unroll
            for (int i = 0; i < 16; ++i) {
                const int F = tid + 256 * i, row = F >> 6, c2 = F & 63;
                const float* xr = x + ((size_t)((b * T_ + tb + row) * J_ + j)) * D_ + 1 + 2 * c2;
                *reinterpret_cast<unsigned*>(&sxg[row * 136 + 2 * c2]) =
                    (unsigned)(unsigned short)f2b(xr[0]) |
                    ((unsigned)(unsigned short)f2b(xr[1]) << 16);
            }
        }
        __syncthreads();   // (A) sx ready; it=0 also covers kvT2/kss/rnorm fills

        // q GEMM
        fx4 acc[2][4];
        #pragma unroll
        for (int nt = 0; nt < 2; ++nt)
            #pragma unroll
            for (int mt = 0; mt < 4; ++mt) acc[nt][mt] = (fx4){0.f, 0.f, 0.f, 0.f};
        #pragma unroll
        for (int ks = 0; ks < 4; ++ks) {
            bf8 af[4];
            #pragma unroll
            for (int mt = 0; mt < 4; ++mt)
                af[mt] = *reinterpret_cast<const bf8*>(
                    &sxg[(mt * 16 + l16) * 136 + ks * 32 + quad * 8]);
            #pragma unroll
            for (int nt = 0; nt < 2; ++nt)
                #pragma unroll
                for (int mt = 0; mt < 4; ++mt)
                    acc[nt][mt] = __builtin_amdgcn_mfma_f32_16x16x32_bf16(
                        af[mt], wqf[nt][ks], acc[nt][mt], 0, 0, 0);
        }
        // phi + write q_m to own column stripe (intra-wave producer/consumer)
        #pragma unroll
        for (int nt = 0; nt < 2; ++nt) {
            const int col = wave * 32 + nt * 16 + l16;
            #pragma unroll
            for (int mt = 0; mt < 4; ++mt)
                #pragma unroll
                for (int r = 0; r < 4; ++r)
                    qm[(mt * 16 + quad * 4 + r) * 136 + col] =
                        f2b(phi_f(acc[nt][mt][r] + bq2[nt]));
        }
        asm volatile("" ::: "memory");   // keep qm writes ordered before agg reads

        // agg = (q_m @ kv[h]) / denom; denom fused as 2 extra MFMAs (ksum hi+lo
        // replicated over cols). agg written in place over qm.
        #pragma unroll
        for (int hh = 0; hh < 2; ++hh) {
            const int h = wave * 2 + hh;
            bf8 bk = (bf8){0, 0, 0, 0, 0, 0, 0, 0};
            bf8 bh = (bf8){0, 0, 0, 0, 0, 0, 0, 0};
            bf8 bl = (bf8){0, 0, 0, 0, 0, 0, 0, 0};
            if (quad < 2) {
                bk = *reinterpret_cast<const bf8*>(&kvT2[((h * 2 + quad) * 16 + l16) * 8]);
                bh = *reinterpret_cast<const bf8*>(&ksshi[h * 16 + quad * 8]);
                bl = *reinterpret_cast<const bf8*>(&ksslo[h * 16 + quad * 8]);
            }
            #pragma unroll
            for (int mt = 0; mt < 4; ++mt) {
                bf8 aq = (bf8){0, 0, 0, 0, 0, 0, 0, 0};
                if (quad < 2)
                    aq = *reinterpret_cast<const bf8*>(
                        &qm[(mt * 16 + l16) * 136 + h * 16 + quad * 8]);
                fx4 ag = __builtin_amdgcn_mfma_f32_16x16x32_bf16(
                    aq, bk, (fx4){0.f, 0.f, 0.f, 0.f}, 0, 0, 0);
                fx4 dd = __builtin_amdgcn_mfma_f32_16x16x32_bf16(
                    aq, bl, (fx4){0.f, 0.f, 0.f, 0.f}, 0, 0, 0);
                dd = __builtin_amdgcn_mfma_f32_16x16x32_bf16(aq, bh, dd, 0, 0, 0);
                #pragma unroll
                for (int r = 0; r < 4; ++r) {
                    const float rin = __builtin_amdgcn_rcpf(fmaxf(dd[r], EPS_));
                    qm[(mt * 16 + quad * 4 + r) * 136 + h * 16 + l16] =
                        f2b(ag[r] * rin);
                }
            }
        }
        __syncthreads();   // (B) agg (in qm) ready for cross-wave out GEMM

        // out GEMM + bias
        fx4 ya[2][4];
        #pragma unroll
        for (int nt = 0; nt < 2; ++nt)
            #pragma unroll
            for (int mt = 0; mt < 4; ++mt) ya[nt][mt] = (fx4){0.f, 0.f, 0.f, 0.f};
        #pragma unroll
        for (int ks = 0; ks < 4; ++ks) {
            bf8 af[4];
            #pragma unroll
            for (int mt = 0; mt < 4; ++mt)
                af[mt] = *reinterpret_cast<const bf8*>(
                    &qm[(mt * 16 + l16) * 136 + ks * 32 + quad * 8]);
            #pragma unroll
            for (int nt = 0; nt < 2; ++nt)
                #pragma unroll
                for (int mt = 0; mt < 4; ++mt)
                    ya[nt][mt] = __builtin_amdgcn_mfma_f32_16x16x32_bf16(
                        af[mt], wof[nt][ks], ya[nt][mt], 0, 0, 0);
        }

        // stores + row-norm
        #pragma unroll
        for (int mt = 0; mt < 4; ++mt) {
            float sq[4] = {0.f, 0.f, 0.f, 0.f};
            #pragma unroll
            for (int nt = 0; nt < 2; ++nt) {
                const int col = wave * 32 + nt * 16 + l16;
                #pragma unroll
                for (int r = 0; r < 4; ++r) {
                    const float y = ya[nt][mt][r] + bo2[nt];
                    const int t = tb + mt * 16 + quad * 4 + r;
                    out[((size_t)(b * T_ + t) * J_ + j) * D_ + 1 + col] = y;
                    sq[r] += y * y;
                }
            }
            #pragma unroll
            for (int r = 0; r < 4; ++r) {
                float s = sq[r];
                s += __shfl_xor(s, 1);
                s += __shfl_xor(s, 2);
                s += __shfl_xor(s, 4);
                s += __shfl_xor(s, 8);
                if (l16 == 0) atomicAdd(&rnorm[mt * 16 + quad * 4 + r], s);
            }
        }
        __syncthreads();   // (C) rnorm complete
        if (tid < 64) {
            const int t = tb + tid;
            out[((size_t)(b * T_ + t) * J_ + j) * D_] = sqrtf(1.f + rnorm[tid]);
            rnorm[tid] = 0.f;   // re-zero for next iter (same threads; ordered by A/B)
        }
    }
}

extern "C" void kernel_launch(void* const* d_in, const int* in_sizes, int n_in,
                              void* d_out, int out_size, void* d_ws, size_t ws_size,
                              hipStream_t stream) {
    const float* x     = (const float*)d_in[0];
    const float* wqkv  = (const float*)d_in[1];
    const float* bqkv  = (const float*)d_in[2];
    const float* wout  = (const float*)d_in[3];
    const float* bout  = (const float*)d_in[4];
    float* out = (float*)d_out;

    float* kvw = (float*)d_ws;                          // BJ*H*16*16 fp32
    float* ksw = kvw + (size_t)BJ_ * H_ * 16 * 16;      // BJ*128 fp32
    const size_t zero_bytes =
        ((size_t)BJ_ * H_ * 16 * 16 + (size_t)BJ_ * d_) * sizeof(float);
    hipMemsetAsync(d_ws, 0, zero_bytes, stream);

    dim3 blk(256);
    dim3 grdK(CHK, BJ_);
    dim3 grdO(CHO, BJ_);
    hipLaunchKernelGGL(pass_kv, grdK, blk, 0, stream, x, wqkv, bqkv, kvw, ksw);
    hipLaunchKernelGGL(pass_out, grdO, blk, 0, stream, x, wqkv, bqkv, wout, bout,
                       kvw, ksw, out);
}

// Round 3
// 437.027 us; speedup vs baseline: 1.4277x; 1.4277x over previous
//
#include <hip/hip_runtime.h>
#include <math.h>

#define B_   8
#define T_   2048
#define J_   17
#define D_   129
#define d_   128
#define H_   8
#define BJ_  (B_ * J_)      // 136
#define EPS_ 1e-6f

#define CHK  16
#define RPBK (T_ / CHK)     // 128 rows per block
#define NITK (RPBK / 64)    // 2
#define CHO  8
#define RPBO (T_ / CHO)     // 256 rows per block
#define NITO (RPBO / 64)    // 4

typedef short bf8 __attribute__((ext_vector_type(8)));   // 8 bf16 in 4 VGPRs
typedef float fx4 __attribute__((ext_vector_type(4)));

__device__ __forceinline__ float phi_f(float x) {
    return x > 0.f ? x + 1.f : __expf(x);
}
__device__ __forceinline__ short f2b(float f) {            // fp32->bf16 RNE
    union { float f; unsigned u; } c; c.f = f;
    unsigned u = c.u + 0x7fffu + ((c.u >> 16) & 1u);
    return (short)(u >> 16);
}
__device__ __forceinline__ float b2f(short s) {
    union { float f; unsigned u; } c;
    c.u = ((unsigned)(unsigned short)s) << 16;
    return c.f;
}
__device__ __forceinline__ bf8 ld_w8(const float* p) {
    const float4* q = reinterpret_cast<const float4*>(p);
    float4 a = q[0], b = q[1];
    bf8 t;
    t[0] = f2b(a.x); t[1] = f2b(a.y); t[2] = f2b(a.z); t[3] = f2b(a.w);
    t[4] = f2b(b.x); t[5] = f2b(b.y); t[6] = f2b(b.z); t[7] = f2b(b.w);
    return t;
}

// ============================================================================
// pack_x: x (B,T,J,129 f32) -> xb[bj][t][128] bf16, once. 214 MB streamed.
// Removes per-pass f2b conversion + enables 16B-aligned staging loads.
// ============================================================================
__global__ __launch_bounds__(256) void pack_x(
        const float* __restrict__ x, unsigned* __restrict__ xb) {
    const unsigned u = blockIdx.x * 256 + threadIdx.x;   // one 2-float unit
    const int c2 = u & 63;
    const int t  = (u >> 6) & (T_ - 1);
    const int bj = u >> 17;                              // T_*64 = 2^17
    const int b = bj / J_, j = bj % J_;
    const float* xr = x + ((size_t)((b * T_ + t) * J_ + j)) * D_ + 1 + 2 * c2;
    xb[((size_t)bj * T_ + t) * 64 + c2] =
        (unsigned)(unsigned short)f2b(xr[0]) |
        ((unsigned)(unsigned short)f2b(xr[1]) << 16);
}

// ============================================================================
// Pass A: k/v GEMM (cols 128..383) + kv[h] += k_m^T v + ksum, per bj.
// XOR-swizzled, pad-free LDS (49152 B -> 3 blocks/CU). No waves-per-EU bound
// (the compiler caps VGPR at 256/N and spills; natural ~140 -> 3 waves/SIMD).
// 2 barriers/iter. acc split in 2 nt-pairs to bound live registers.
// ============================================================================
__global__ __launch_bounds__(256) void pass_kv(
        const float* __restrict__ x, const short* __restrict__ xb,
        const int packed,
        const float* __restrict__ wqkv, const float* __restrict__ bqkv,
        float* __restrict__ kvw,       // [BJ][H][16(j=v-feat)][16(i=k-feat)]
        float* __restrict__ ksw) {     // [BJ][128]
    const int bj = blockIdx.y, b = bj / J_, j = bj % J_;
    const int t0 = blockIdx.x * RPBK;
    const int tid = threadIdx.x, wave = tid >> 6, lane = tid & 63;
    const int quad = lane >> 4, l16 = lane & 15;
    const int rsw = (l16 & 7) << 4;                  // row-XOR for frag rows

    __shared__ __align__(16) short sx[64 * 128];     // 16384 B, swizzled
    __shared__ __align__(16) short kT[128 * 64];     // 16384 B, swizzled
    __shared__ __align__(16) short vT[128 * 64];     // 16384 B, swizzled

    bf8 wf[4][4];
    float bias[4];
    #pragma unroll
    for (int nt = 0; nt < 4; ++nt) {
        const int n = d_ + wave * 64 + nt * 16 + l16;
        bias[nt] = bqkv[n];
        #pragma unroll
        for (int ks = 0; ks < 4; ++ks)
            wf[nt][ks] = ld_w8(wqkv + (size_t)n * d_ + ks * 32 + quad * 8);
    }

    fx4 kva[2];
    kva[0] = (fx4){0.f, 0.f, 0.f, 0.f};
    kva[1] = (fx4){0.f, 0.f, 0.f, 0.f};
    float ksp[4] = {0.f, 0.f, 0.f, 0.f};

    for (int it = 0; it < NITK; ++it) {
        const int tb = t0 + it * 64;
        if (packed) {
            const short* src = xb + ((size_t)bj * T_ + tb) * d_;
            #pragma unroll
            for (int u = 0; u < 4; ++u) {
                const int chunk = tid + 256 * u;           // 0..1023 (16B units)
                const int row = chunk >> 4, cb = (chunk & 15) << 4;
                bf8 v = *reinterpret_cast<const bf8*>(src + row * d_ + (cb >> 1));
                *reinterpret_cast<bf8*>(reinterpret_cast<char*>(sx) +
                    row * 256 + (cb ^ ((row & 7) << 4))) = v;
            }
        } else {
            #pragma unroll
            for (int i = 0; i < 16; ++i) {
                const int F = tid + 256 * i, row = F >> 6, c2 = F & 63;
                const float* xr = x + ((size_t)((b * T_ + tb + row) * J_ + j)) * D_ + 1 + 2 * c2;
                const unsigned w = (unsigned)(unsigned short)f2b(xr[0]) |
                                   ((unsigned)(unsigned short)f2b(xr[1]) << 16);
                *reinterpret_cast<unsigned*>(reinterpret_cast<char*>(sx) +
                    row * 256 + ((c2 * 4) ^ ((row & 7) << 4))) = w;
            }
        }
        __syncthreads();   // sx ready; also orders prev-iter kvMFMA vs kT/vT writes

        short* dst = (wave < 2) ? kT : vT;
        const int fbase = (wave & 1) * 64;
        const bool isk = (wave < 2);

        #pragma unroll
        for (int pr = 0; pr < 2; ++pr) {           // nt pair {2pr, 2pr+1}
            fx4 acc[2][4];
            #pragma unroll
            for (int n2 = 0; n2 < 2; ++n2)
                #pragma unroll
                for (int mt = 0; mt < 4; ++mt) acc[n2][mt] = (fx4){0.f, 0.f, 0.f, 0.f};

            #pragma unroll
            for (int ks = 0; ks < 4; ++ks) {
                bf8 af[4];
                #pragma unroll
                for (int mt = 0; mt < 4; ++mt)
                    af[mt] = *reinterpret_cast<const bf8*>(
                        reinterpret_cast<char*>(sx) + (mt * 16 + l16) * 256 +
                        ((ks * 64 + quad * 16) ^ rsw));
                #pragma unroll
                for (int n2 = 0; n2 < 2; ++n2)
                    #pragma unroll
                    for (int mt = 0; mt < 4; ++mt)
                        acc[n2][mt] = __builtin_amdgcn_mfma_f32_16x16x32_bf16(
                            af[mt], wf[pr * 2 + n2][ks], acc[n2][mt], 0, 0, 0);
            }

            // epilogue: bias (+phi for k), transpose-write to kT / vT (swizzled)
            #pragma unroll
            for (int n2 = 0; n2 < 2; ++n2) {
                const int nt = pr * 2 + n2;
                const int feat = fbase + nt * 16 + l16;    // feat&7 == l16&7
                #pragma unroll
                for (int mt = 0; mt < 4; ++mt) {
                    unsigned long long pk = 0ull;
                    #pragma unroll
                    for (int r = 0; r < 4; ++r) {
                        float v = acc[n2][mt][r] + bias[nt];
                        if (isk) { v = phi_f(v); ksp[nt] += v; }
                        pk |= ((unsigned long long)(unsigned short)f2b(v)) << (16 * r);
                    }
                    *reinterpret_cast<unsigned long long*>(
                        reinterpret_cast<char*>(dst) + feat * 128 +
                        ((mt * 32 + quad * 8) ^ rsw)) = pk;
                }
            }
        }
        __syncthreads();   // kT/vT ready (cross-wave)

        // kv[h] += k_m^T(16 x 64t) * v(64t x 16): K = t, two 32-steps
        #pragma unroll
        for (int hh = 0; hh < 2; ++hh) {
            const int h = wave * 2 + hh;
            const int feat = h * 16 + l16;                 // feat&7 == l16&7
            #pragma unroll
            for (int ks2 = 0; ks2 < 2; ++ks2) {
                bf8 ak = *reinterpret_cast<const bf8*>(
                    reinterpret_cast<char*>(kT) + feat * 128 +
                    ((ks2 * 64 + quad * 16) ^ rsw));
                bf8 bv = *reinterpret_cast<const bf8*>(
                    reinterpret_cast<char*>(vT) + feat * 128 +
                    ((ks2 * 64 + quad * 16) ^ rsw));
                kva[hh] = __builtin_amdgcn_mfma_f32_16x16x32_bf16(ak, bv, kva[hh], 0, 0, 0);
            }
        }
    }

    #pragma unroll
    for (int hh = 0; hh < 2; ++hh) {
        const int h = wave * 2 + hh;
        float* p = kvw + (((size_t)bj * H_ + h) * 16 + l16) * 16 + quad * 4;
        #pragma unroll
        for (int r = 0; r < 4; ++r) atomicAdd(p + r, kva[hh][r]);
    }
    if (wave < 2) {
        #pragma unroll
        for (int nt = 0; nt < 4; ++nt) {
            float s = ksp[nt];
            s += __shfl_xor(s, 16);
            s += __shfl_xor(s, 32);
            if (lane < 16)
                atomicAdd(ksw + (size_t)bj * d_ + wave * 64 + nt * 16 + l16, s);
        }
    }
}

// ============================================================================
// Pass B: q GEMM -> phi -> [agg + denom via fused MFMA] -> out GEMM -> store.
// Round-1 verified logic; LDS 38656 B + VGPR<=128 (cap from (256,2)) -> 4 blk/CU.
// sxg swizzled; qm kept padded (2B scatter writes). 3 barriers/iter.
// ============================================================================
__global__ __launch_bounds__(256, 2) void pass_out(
        const float* __restrict__ x, const short* __restrict__ xb,
        const int packed,
        const float* __restrict__ wqkv, const float* __restrict__ bqkv,
        const float* __restrict__ wout, const float* __restrict__ bout,
        const float* __restrict__ kvw, const float* __restrict__ ksw,
        float* __restrict__ out) {
    const int bj = blockIdx.y, b = bj / J_, j = bj % J_;
    const int t0 = blockIdx.x * RPBO;
    const int tid = threadIdx.x, wave = tid >> 6, lane = tid & 63;
    const int quad = lane >> 4, l16 = lane & 15;
    const int rsw = (l16 & 7) << 4;

    __shared__ __align__(16) short sxg[64 * 128];        // 16384 B, swizzled
    __shared__ __align__(16) short qm[64 * 136];         // q_m, then agg in-place
    __shared__ __align__(16) short kvT2[H_ * 2 * 16 * 8];// [h][qd][jv][8] (4096 B)
    __shared__ __align__(16) short ksshi[d_];
    __shared__ __align__(16) short ksslo[d_];
    __shared__ float rnorm[64];

    bf8 wqf[2][4], wof[2][4];
    float bq2[2], bo2[2];
    #pragma unroll
    for (int nt = 0; nt < 2; ++nt) {
        const int n = wave * 32 + nt * 16 + l16;
        bq2[nt] = bqkv[n];
        bo2[nt] = bout[n];
        #pragma unroll
        for (int ks = 0; ks < 4; ++ks) {
            wqf[nt][ks] = ld_w8(wqkv + (size_t)n * d_ + ks * 32 + quad * 8);
            wof[nt][ks] = ld_w8(wout + (size_t)n * d_ + ks * 32 + quad * 8);
        }
    }
    #pragma unroll
    for (int u = 0; u < 8; ++u) {
        const int lin = tid + 256 * u;                   // 0..2047
        const int jj = lin & 7, jv = (lin >> 3) & 15, qd = (lin >> 7) & 1, h = lin >> 8;
        kvT2[lin] = f2b(kvw[(((size_t)bj * H_ + h) * 16 + jv) * 16 + qd * 8 + jj]);
    }
    if (tid < d_) {                                      // ksum hi/lo split
        const float v = ksw[(size_t)bj * d_ + tid];
        const short hi = f2b(v);
        ksshi[tid] = hi;
        ksslo[tid] = f2b(v - b2f(hi));
    }
    if (tid < 64) rnorm[tid] = 0.f;

    for (int it = 0; it < NITO; ++it) {
        const int tb = t0 + it * 64;
        if (packed) {
            const short* src = xb + ((size_t)bj * T_ + tb) * d_;
            #pragma unroll
            for (int u = 0; u < 4; ++u) {
                const int chunk = tid + 256 * u;
                const int row = chunk >> 4, cb = (chunk & 15) << 4;
                bf8 v = *reinterpret_cast<const bf8*>(src + row * d_ + (cb >> 1));
                *reinterpret_cast<bf8*>(reinterpret_cast<char*>(sxg) +
                    row * 256 + (cb ^ ((row & 7) << 4))) = v;
            }
        } else {
            #pragma unroll
            for (int i = 0; i < 16; ++i) {
                const int F = tid + 256 * i, row = F >> 6, c2 = F & 63;
                const float* xr = x + ((size_t)((b * T_ + tb + row) * J_ + j)) * D_ + 1 + 2 * c2;
                const unsigned w = (unsigned)(unsigned short)f2b(xr[0]) |
                                   ((unsigned)(unsigned short)f2b(xr[1]) << 16);
                *reinterpret_cast<unsigned*>(reinterpret_cast<char*>(sxg) +
                    row * 256 + ((c2 * 4) ^ ((row & 7) << 4))) = w;
            }
        }
        __syncthreads();   // (A) sxg ready; it=0 also covers kvT2/kss/rnorm fills

        // q GEMM
        fx4 acc[2][4];
        #pragma unroll
        for (int nt = 0; nt < 2; ++nt)
            #pragma unroll
            for (int mt = 0; mt < 4; ++mt) acc[nt][mt] = (fx4){0.f, 0.f, 0.f, 0.f};
        #pragma unroll
        for (int ks = 0; ks < 4; ++ks) {
            bf8 af[4];
            #pragma unroll
            for (int mt = 0; mt < 4; ++mt)
                af[mt] = *reinterpret_cast<const bf8*>(
                    reinterpret_cast<char*>(sxg) + (mt * 16 + l16) * 256 +
                    ((ks * 64 + quad * 16) ^ rsw));
            #pragma unroll
            for (int nt = 0; nt < 2; ++nt)
                #pragma unroll
                for (int mt = 0; mt < 4; ++mt)
                    acc[nt][mt] = __builtin_amdgcn_mfma_f32_16x16x32_bf16(
                        af[mt], wqf[nt][ks], acc[nt][mt], 0, 0, 0);
        }
        // phi + write q_m to own column stripe (intra-wave producer/consumer)
        #pragma unroll
        for (int nt = 0; nt < 2; ++nt) {
            const int col = wave * 32 + nt * 16 + l16;
            #pragma unroll
            for (int mt = 0; mt < 4; ++mt)
                #pragma unroll
                for (int r = 0; r < 4; ++r)
                    qm[(mt * 16 + quad * 4 + r) * 136 + col] =
                        f2b(phi_f(acc[nt][mt][r] + bq2[nt]));
        }
        asm volatile("" ::: "memory");

        // agg = (q_m @ kv[h]) / denom; denom fused as 2 extra MFMAs.
        #pragma unroll
        for (int hh = 0; hh < 2; ++hh) {
            const int h = wave * 2 + hh;
            bf8 bk = (bf8){0, 0, 0, 0, 0, 0, 0, 0};
            bf8 bh = (bf8){0, 0, 0, 0, 0, 0, 0, 0};
            bf8 bl = (bf8){0, 0, 0, 0, 0, 0, 0, 0};
            if (quad < 2) {
                bk = *reinterpret_cast<const bf8*>(&kvT2[((h * 2 + quad) * 16 + l16) * 8]);
                bh = *reinterpret_cast<const bf8*>(&ksshi[h * 16 + quad * 8]);
                bl = *reinterpret_cast<const bf8*>(&ksslo[h * 16 + quad * 8]);
            }
            #pragma unroll
            for (int mt = 0; mt < 4; ++mt) {
                bf8 aq = (bf8){0, 0, 0, 0, 0, 0, 0, 0};
                if (quad < 2)
                    aq = *reinterpret_cast<const bf8*>(
                        &qm[(mt * 16 + l16) * 136 + h * 16 + quad * 8]);
                fx4 ag = __builtin_amdgcn_mfma_f32_16x16x32_bf16(
                    aq, bk, (fx4){0.f, 0.f, 0.f, 0.f}, 0, 0, 0);
                fx4 dd = __builtin_amdgcn_mfma_f32_16x16x32_bf16(
                    aq, bl, (fx4){0.f, 0.f, 0.f, 0.f}, 0, 0, 0);
                dd = __builtin_amdgcn_mfma_f32_16x16x32_bf16(aq, bh, dd, 0, 0, 0);
                #pragma unroll
                for (int r = 0; r < 4; ++r) {
                    const float rin = __builtin_amdgcn_rcpf(fmaxf(dd[r], EPS_));
                    qm[(mt * 16 + quad * 4 + r) * 136 + h * 16 + l16] =
                        f2b(ag[r] * rin);
                }
            }
        }
        __syncthreads();   // (B) agg (in qm) ready for cross-wave out GEMM

        // out GEMM + bias
        fx4 ya[2][4];
        #pragma unroll
        for (int nt = 0; nt < 2; ++nt)
            #pragma unroll
            for (int mt = 0; mt < 4; ++mt) ya[nt][mt] = (fx4){0.f, 0.f, 0.f, 0.f};
        #pragma unroll
        for (int ks = 0; ks < 4; ++ks) {
            bf8 af[4];
            #pragma unroll
            for (int mt = 0; mt < 4; ++mt)
                af[mt] = *reinterpret_cast<const bf8*>(
                    &qm[(mt * 16 + l16) * 136 + ks * 32 + quad * 8]);
            #pragma unroll
            for (int nt = 0; nt < 2; ++nt)
                #pragma unroll
                for (int mt = 0; mt < 4; ++mt)
                    ya[nt][mt] = __builtin_amdgcn_mfma_f32_16x16x32_bf16(
                        af[mt], wof[nt][ks], ya[nt][mt], 0, 0, 0);
        }

        // stores + row-norm
        #pragma unroll
        for (int mt = 0; mt < 4; ++mt) {
            float sq[4] = {0.f, 0.f, 0.f, 0.f};
            #pragma unroll
            for (int nt = 0; nt < 2; ++nt) {
                const int col = wave * 32 + nt * 16 + l16;
                #pragma unroll
                for (int r = 0; r < 4; ++r) {
                    const float y = ya[nt][mt][r] + bo2[nt];
                    const int t = tb + mt * 16 + quad * 4 + r;
                    out[((size_t)(b * T_ + t) * J_ + j) * D_ + 1 + col] = y;
                    sq[r] += y * y;
                }
            }
            #pragma unroll
            for (int r = 0; r < 4; ++r) {
                float s = sq[r];
                s += __shfl_xor(s, 1);
                s += __shfl_xor(s, 2);
                s += __shfl_xor(s, 4);
                s += __shfl_xor(s, 8);
                if (l16 == 0) atomicAdd(&rnorm[mt * 16 + quad * 4 + r], s);
            }
        }
        __syncthreads();   // (C) rnorm complete
        if (tid < 64) {
            const int t = tb + tid;
            out[((size_t)(b * T_ + t) * J_ + j) * D_] = sqrtf(1.f + rnorm[tid]);
            rnorm[tid] = 0.f;
        }
    }
}

extern "C" void kernel_launch(void* const* d_in, const int* in_sizes, int n_in,
                              void* d_out, int out_size, void* d_ws, size_t ws_size,
                              hipStream_t stream) {
    const float* x     = (const float*)d_in[0];
    const float* wqkv  = (const float*)d_in[1];
    const float* bqkv  = (const float*)d_in[2];
    const float* wout  = (const float*)d_in[3];
    const float* bout  = (const float*)d_in[4];
    float* out = (float*)d_out;

    float* kvw = (float*)d_ws;                          // BJ*H*16*16 fp32
    float* ksw = kvw + (size_t)BJ_ * H_ * 16 * 16;      // BJ*128 fp32
    const size_t zero_bytes =
        ((size_t)BJ_ * H_ * 16 * 16 + (size_t)BJ_ * d_) * sizeof(float);
    hipMemsetAsync(d_ws, 0, zero_bytes, stream);

    // Optional bf16-packed x in workspace (71 MB). Fallback if ws too small.
    short* xb = (short*)((char*)d_ws + zero_bytes);     // 16B-aligned (1183744 B)
    const size_t xb_bytes = (size_t)BJ_ * T_ * d_ * sizeof(short);
    const int packed = (ws_size >= zero_bytes + xb_bytes) ? 1 : 0;

    dim3 blk(256);
    if (packed) {
        const unsigned units = (unsigned)BJ_ * T_ * 64;   // 2-float units
        hipLaunchKernelGGL(pack_x, dim3(units / 256), blk, 0, stream,
                           x, (unsigned*)xb);
    }

    dim3 grdK(CHK, BJ_);
    dim3 grdO(CHO, BJ_);
    hipLaunchKernelGGL(pass_kv, grdK, blk, 0, stream, x, xb, packed,
                       wqkv, bqkv, kvw, ksw);
    hipLaunchKernelGGL(pass_out, grdO, blk, 0, stream, x, xb, packed,
                       wqkv, bqkv, wout, bout, kvw, ksw, out);
}

// Round 4
// 373.164 us; speedup vs baseline: 1.6720x; 1.1711x over previous
//
#include <hip/hip_runtime.h>
#include <hip/hip_bf16.h>
#include <math.h>

#define B_   8
#define T_   2048
#define J_   17
#define D_   129
#define d_   128
#define H_   8
#define BJ_  (B_ * J_)      // 136
#define EPS_ 1e-6f

#define CHK  8
#define RPBK (T_ / CHK)     // 256 rows per block
#define NITK (RPBK / 64)    // 4
#define CHO  8
#define RPBO (T_ / CHO)     // 256 rows per block
#define NITO (RPBO / 64)    // 4

typedef short bf8 __attribute__((ext_vector_type(8)));   // 8 bf16 in 4 VGPRs
typedef float fx4 __attribute__((ext_vector_type(4)));

__device__ __forceinline__ float phi_f(float x) {
    return x > 0.f ? x + 1.f : __expf(x);
}
// HW bf16 conversion (v_cvt_pk_bf16_f32) — m240: never hand-roll the RNE.
__device__ __forceinline__ short f2b(float f) {
    __hip_bfloat16 h = __float2bfloat16(f);
    return *reinterpret_cast<short*>(&h);
}
__device__ __forceinline__ unsigned f2b2(float lo, float hi) {
    float2 p; p.x = lo; p.y = hi;
    __hip_bfloat162 h2 = __float22bfloat162_rn(p);
    return *reinterpret_cast<unsigned*>(&h2);
}
__device__ __forceinline__ float b2f(short s) {
    union { float f; unsigned u; } c;
    c.u = ((unsigned)(unsigned short)s) << 16;
    return c.f;
}
__device__ __forceinline__ bf8 ld_w8(const float* p) {   // 16B-aligned rows
    const float4* q = reinterpret_cast<const float4*>(p);
    float4 a = q[0], b = q[1];
    bf8 t;
    unsigned* tu = reinterpret_cast<unsigned*>(&t);
    tu[0] = f2b2(a.x, a.y); tu[1] = f2b2(a.z, a.w);
    tu[2] = f2b2(b.x, b.y); tu[3] = f2b2(b.z, b.w);
    return t;
}

// ============================================================================
// Pass A: k/v GEMM (cols 128..383) + kv[h] += k_m^T v + ksum, per bj.
// Swizzled, pad-free LDS (49152 B -> 3 blocks/CU); natural VGPR ~120.
// 2 barriers/iter; acc split in 2 nt-pairs; HW-cast staging from fp32 x.
// ============================================================================
__global__ __launch_bounds__(256) void pass_kv(
        const float* __restrict__ x,
        const float* __restrict__ wqkv, const float* __restrict__ bqkv,
        float* __restrict__ kvw,       // [BJ][H][16(j=v-feat)][16(i=k-feat)]
        float* __restrict__ ksw) {     // [BJ][128]
    const int bj = blockIdx.y, b = bj / J_, j = bj % J_;
    const int t0 = blockIdx.x * RPBK;
    const int tid = threadIdx.x, wave = tid >> 6, lane = tid & 63;
    const int quad = lane >> 4, l16 = lane & 15;
    const int rsw = (l16 & 7) << 4;                  // row-XOR for frag rows

    __shared__ __align__(16) short sx[64 * 128];     // 16384 B, swizzled
    __shared__ __align__(16) short kT[128 * 64];     // 16384 B, swizzled
    __shared__ __align__(16) short vT[128 * 64];     // 16384 B, swizzled

    bf8 wf[4][4];
    float bias[4];
    #pragma unroll
    for (int nt = 0; nt < 4; ++nt) {
        const int n = d_ + wave * 64 + nt * 16 + l16;
        bias[nt] = bqkv[n];
        #pragma unroll
        for (int ks = 0; ks < 4; ++ks)
            wf[nt][ks] = ld_w8(wqkv + (size_t)n * d_ + ks * 32 + quad * 8);
    }

    fx4 kva[2];
    kva[0] = (fx4){0.f, 0.f, 0.f, 0.f};
    kva[1] = (fx4){0.f, 0.f, 0.f, 0.f};
    float ksp[4] = {0.f, 0.f, 0.f, 0.f};

    for (int it = 0; it < NITK; ++it) {
        const int tb = t0 + it * 64;
        {   // stage x tile -> bf16 LDS (HW cvt_pk pairs)
            #pragma unroll
            for (int i = 0; i < 16; ++i) {
                const int F = tid + 256 * i, row = F >> 6, c2 = F & 63;
                const float* xr = x + ((size_t)((b * T_ + tb + row) * J_ + j)) * D_ + 1 + 2 * c2;
                *reinterpret_cast<unsigned*>(reinterpret_cast<char*>(sx) +
                    row * 256 + ((c2 * 4) ^ ((row & 7) << 4))) = f2b2(xr[0], xr[1]);
            }
        }
        __syncthreads();   // sx ready; also orders prev-iter kvMFMA vs kT/vT writes

        short* dst = (wave < 2) ? kT : vT;
        const int fbase = (wave & 1) * 64;
        const bool isk = (wave < 2);

        #pragma unroll
        for (int pr = 0; pr < 2; ++pr) {           // nt pair {2pr, 2pr+1}
            fx4 acc[2][4];
            #pragma unroll
            for (int n2 = 0; n2 < 2; ++n2)
                #pragma unroll
                for (int mt = 0; mt < 4; ++mt) acc[n2][mt] = (fx4){0.f, 0.f, 0.f, 0.f};

            #pragma unroll
            for (int ks = 0; ks < 4; ++ks) {
                bf8 af[4];
                #pragma unroll
                for (int mt = 0; mt < 4; ++mt)
                    af[mt] = *reinterpret_cast<const bf8*>(
                        reinterpret_cast<char*>(sx) + (mt * 16 + l16) * 256 +
                        ((ks * 64 + quad * 16) ^ rsw));
                #pragma unroll
                for (int n2 = 0; n2 < 2; ++n2)
                    #pragma unroll
                    for (int mt = 0; mt < 4; ++mt)
                        acc[n2][mt] = __builtin_amdgcn_mfma_f32_16x16x32_bf16(
                            af[mt], wf[pr * 2 + n2][ks], acc[n2][mt], 0, 0, 0);
            }

            // epilogue: bias (+phi for k), transpose-write to kT / vT (swizzled)
            #pragma unroll
            for (int n2 = 0; n2 < 2; ++n2) {
                const int nt = pr * 2 + n2;
                const int feat = fbase + nt * 16 + l16;    // feat&7 == l16&7
                #pragma unroll
                for (int mt = 0; mt < 4; ++mt) {
                    float v0 = acc[n2][mt][0] + bias[nt];
                    float v1 = acc[n2][mt][1] + bias[nt];
                    float v2 = acc[n2][mt][2] + bias[nt];
                    float v3 = acc[n2][mt][3] + bias[nt];
                    if (isk) {
                        v0 = phi_f(v0); v1 = phi_f(v1);
                        v2 = phi_f(v2); v3 = phi_f(v3);
                        ksp[nt] += (v0 + v1) + (v2 + v3);
                    }
                    const unsigned lo = f2b2(v0, v1), hi = f2b2(v2, v3);
                    *reinterpret_cast<unsigned long long*>(
                        reinterpret_cast<char*>(dst) + feat * 128 +
                        ((mt * 32 + quad * 8) ^ rsw)) =
                        (unsigned long long)lo | ((unsigned long long)hi << 32);
                }
            }
        }
        __syncthreads();   // kT/vT ready (cross-wave)

        // kv[h] += k_m^T(16 x 64t) * v(64t x 16): K = t, two 32-steps
        #pragma unroll
        for (int hh = 0; hh < 2; ++hh) {
            const int h = wave * 2 + hh;
            const int feat = h * 16 + l16;                 // feat&7 == l16&7
            #pragma unroll
            for (int ks2 = 0; ks2 < 2; ++ks2) {
                bf8 ak = *reinterpret_cast<const bf8*>(
                    reinterpret_cast<char*>(kT) + feat * 128 +
                    ((ks2 * 64 + quad * 16) ^ rsw));
                bf8 bv = *reinterpret_cast<const bf8*>(
                    reinterpret_cast<char*>(vT) + feat * 128 +
                    ((ks2 * 64 + quad * 16) ^ rsw));
                kva[hh] = __builtin_amdgcn_mfma_f32_16x16x32_bf16(ak, bv, kva[hh], 0, 0, 0);
            }
        }
    }

    #pragma unroll
    for (int hh = 0; hh < 2; ++hh) {
        const int h = wave * 2 + hh;
        float* p = kvw + (((size_t)bj * H_ + h) * 16 + l16) * 16 + quad * 4;
        #pragma unroll
        for (int r = 0; r < 4; ++r) atomicAdd(p + r, kva[hh][r]);
    }
    if (wave < 2) {
        #pragma unroll
        for (int nt = 0; nt < 4; ++nt) {
            float s = ksp[nt];
            s += __shfl_xor(s, 16);
            s += __shfl_xor(s, 32);
            if (lane < 16)
                atomicAdd(ksw + (size_t)bj * d_ + wave * 64 + nt * 16 + l16, s);
        }
    }
}

// ============================================================================
// Pass B: q GEMM -> phi -> [agg + denom via fused MFMA] -> out GEMM -> store.
// LDS 38656 B, VGPR<=128 (cap from (256,2), natural ~116) -> 4 blocks/CU.
// 3 barriers/iter; HW-cast staging/epilogues.
// ============================================================================
__global__ __launch_bounds__(256, 2) void pass_out(
        const float* __restrict__ x,
        const float* __restrict__ wqkv, const float* __restrict__ bqkv,
        const float* __restrict__ wout, const float* __restrict__ bout,
        const float* __restrict__ kvw, const float* __restrict__ ksw,
        float* __restrict__ out) {
    const int bj = blockIdx.y, b = bj / J_, j = bj % J_;
    const int t0 = blockIdx.x * RPBO;
    const int tid = threadIdx.x, wave = tid >> 6, lane = tid & 63;
    const int quad = lane >> 4, l16 = lane & 15;
    const int rsw = (l16 & 7) << 4;

    __shared__ __align__(16) short sxg[64 * 128];        // 16384 B, swizzled
    __shared__ __align__(16) short qm[64 * 136];         // q_m, then agg in-place
    __shared__ __align__(16) short kvT2[H_ * 2 * 16 * 8];// [h][qd][jv][8] (4096 B)
    __shared__ __align__(16) short ksshi[d_];
    __shared__ __align__(16) short ksslo[d_];
    __shared__ float rnorm[64];

    bf8 wqf[2][4], wof[2][4];
    float bq2[2], bo2[2];
    #pragma unroll
    for (int nt = 0; nt < 2; ++nt) {
        const int n = wave * 32 + nt * 16 + l16;
        bq2[nt] = bqkv[n];
        bo2[nt] = bout[n];
        #pragma unroll
        for (int ks = 0; ks < 4; ++ks) {
            wqf[nt][ks] = ld_w8(wqkv + (size_t)n * d_ + ks * 32 + quad * 8);
            wof[nt][ks] = ld_w8(wout + (size_t)n * d_ + ks * 32 + quad * 8);
        }
    }
    #pragma unroll
    for (int u = 0; u < 8; ++u) {
        const int lin = tid + 256 * u;                   // 0..2047
        const int jj = lin & 7, jv = (lin >> 3) & 15, qd = (lin >> 7) & 1, h = lin >> 8;
        kvT2[lin] = f2b(kvw[(((size_t)bj * H_ + h) * 16 + jv) * 16 + qd * 8 + jj]);
    }
    if (tid < d_) {                                      // ksum hi/lo split
        const float v = ksw[(size_t)bj * d_ + tid];
        const short hi = f2b(v);
        ksshi[tid] = hi;
        ksslo[tid] = f2b(v - b2f(hi));
    }
    if (tid < 64) rnorm[tid] = 0.f;

    for (int it = 0; it < NITO; ++it) {
        const int tb = t0 + it * 64;
        {   // stage x tile
            #pragma unroll
            for (int i = 0; i < 16; ++i) {
                const int F = tid + 256 * i, row = F >> 6, c2 = F & 63;
                const float* xr = x + ((size_t)((b * T_ + tb + row) * J_ + j)) * D_ + 1 + 2 * c2;
                *reinterpret_cast<unsigned*>(reinterpret_cast<char*>(sxg) +
                    row * 256 + ((c2 * 4) ^ ((row & 7) << 4))) = f2b2(xr[0], xr[1]);
            }
        }
        __syncthreads();   // (A) sxg ready; it=0 also covers kvT2/kss/rnorm fills

        // q GEMM
        fx4 acc[2][4];
        #pragma unroll
        for (int nt = 0; nt < 2; ++nt)
            #pragma unroll
            for (int mt = 0; mt < 4; ++mt) acc[nt][mt] = (fx4){0.f, 0.f, 0.f, 0.f};
        #pragma unroll
        for (int ks = 0; ks < 4; ++ks) {
            bf8 af[4];
            #pragma unroll
            for (int mt = 0; mt < 4; ++mt)
                af[mt] = *reinterpret_cast<const bf8*>(
                    reinterpret_cast<char*>(sxg) + (mt * 16 + l16) * 256 +
                    ((ks * 64 + quad * 16) ^ rsw));
            #pragma unroll
            for (int nt = 0; nt < 2; ++nt)
                #pragma unroll
                for (int mt = 0; mt < 4; ++mt)
                    acc[nt][mt] = __builtin_amdgcn_mfma_f32_16x16x32_bf16(
                        af[mt], wqf[nt][ks], acc[nt][mt], 0, 0, 0);
        }
        // phi + write q_m to own column stripe (intra-wave producer/consumer)
        #pragma unroll
        for (int nt = 0; nt < 2; ++nt) {
            const int col = wave * 32 + nt * 16 + l16;
            #pragma unroll
            for (int mt = 0; mt < 4; ++mt)
                #pragma unroll
                for (int r = 0; r < 4; ++r)
                    qm[(mt * 16 + quad * 4 + r) * 136 + col] =
                        f2b(phi_f(acc[nt][mt][r] + bq2[nt]));
        }
        asm volatile("" ::: "memory");

        // agg = (q_m @ kv[h]) / denom; denom fused as 2 extra MFMAs.
        #pragma unroll
        for (int hh = 0; hh < 2; ++hh) {
            const int h = wave * 2 + hh;
            bf8 bk = (bf8){0, 0, 0, 0, 0, 0, 0, 0};
            bf8 bh = (bf8){0, 0, 0, 0, 0, 0, 0, 0};
            bf8 bl = (bf8){0, 0, 0, 0, 0, 0, 0, 0};
            if (quad < 2) {
                bk = *reinterpret_cast<const bf8*>(&kvT2[((h * 2 + quad) * 16 + l16) * 8]);
                bh = *reinterpret_cast<const bf8*>(&ksshi[h * 16 + quad * 8]);
                bl = *reinterpret_cast<const bf8*>(&ksslo[h * 16 + quad * 8]);
            }
            #pragma unroll
            for (int mt = 0; mt < 4; ++mt) {
                bf8 aq = (bf8){0, 0, 0, 0, 0, 0, 0, 0};
                if (quad < 2)
                    aq = *reinterpret_cast<const bf8*>(
                        &qm[(mt * 16 + l16) * 136 + h * 16 + quad * 8]);
                fx4 ag = __builtin_amdgcn_mfma_f32_16x16x32_bf16(
                    aq, bk, (fx4){0.f, 0.f, 0.f, 0.f}, 0, 0, 0);
                fx4 dd = __builtin_amdgcn_mfma_f32_16x16x32_bf16(
                    aq, bl, (fx4){0.f, 0.f, 0.f, 0.f}, 0, 0, 0);
                dd = __builtin_amdgcn_mfma_f32_16x16x32_bf16(aq, bh, dd, 0, 0, 0);
                #pragma unroll
                for (int r = 0; r < 4; ++r) {
                    const float rin = __builtin_amdgcn_rcpf(fmaxf(dd[r], EPS_));
                    qm[(mt * 16 + quad * 4 + r) * 136 + h * 16 + l16] =
                        f2b(ag[r] * rin);
                }
            }
        }
        __syncthreads();   // (B) agg (in qm) ready for cross-wave out GEMM

        // out GEMM + bias
        fx4 ya[2][4];
        #pragma unroll
        for (int nt = 0; nt < 2; ++nt)
            #pragma unroll
            for (int mt = 0; mt < 4; ++mt) ya[nt][mt] = (fx4){0.f, 0.f, 0.f, 0.f};
        #pragma unroll
        for (int ks = 0; ks < 4; ++ks) {
            bf8 af[4];
            #pragma unroll
            for (int mt = 0; mt < 4; ++mt)
                af[mt] = *reinterpret_cast<const bf8*>(
                    &qm[(mt * 16 + l16) * 136 + ks * 32 + quad * 8]);
            #pragma unroll
            for (int nt = 0; nt < 2; ++nt)
                #pragma unroll
                for (int mt = 0; mt < 4; ++mt)
                    ya[nt][mt] = __builtin_amdgcn_mfma_f32_16x16x32_bf16(
                        af[mt], wof[nt][ks], ya[nt][mt], 0, 0, 0);
        }

        // stores + row-norm
        #pragma unroll
        for (int mt = 0; mt < 4; ++mt) {
            float sq[4] = {0.f, 0.f, 0.f, 0.f};
            #pragma unroll
            for (int nt = 0; nt < 2; ++nt) {
                const int col = wave * 32 + nt * 16 + l16;
                #pragma unroll
                for (int r = 0; r < 4; ++r) {
                    const float y = ya[nt][mt][r] + bo2[nt];
                    const int t = tb + mt * 16 + quad * 4 + r;
                    out[((size_t)(b * T_ + t) * J_ + j) * D_ + 1 + col] = y;
                    sq[r] += y * y;
                }
            }
            #pragma unroll
            for (int r = 0; r < 4; ++r) {
                float s = sq[r];
                s += __shfl_xor(s, 1);
                s += __shfl_xor(s, 2);
                s += __shfl_xor(s, 4);
                s += __shfl_xor(s, 8);
                if (l16 == 0) atomicAdd(&rnorm[mt * 16 + quad * 4 + r], s);
            }
        }
        __syncthreads();   // (C) rnorm complete
        if (tid < 64) {
            const int t = tb + tid;
            out[((size_t)(b * T_ + t) * J_ + j) * D_] = sqrtf(1.f + rnorm[tid]);
            rnorm[tid] = 0.f;
        }
    }
}

extern "C" void kernel_launch(void* const* d_in, const int* in_sizes, int n_in,
                              void* d_out, int out_size, void* d_ws, size_t ws_size,
                              hipStream_t stream) {
    const float* x     = (const float*)d_in[0];
    const float* wqkv  = (const float*)d_in[1];
    const float* bqkv  = (const float*)d_in[2];
    const float* wout  = (const float*)d_in[3];
    const float* bout  = (const float*)d_in[4];
    float* out = (float*)d_out;

    float* kvw = (float*)d_ws;                          // BJ*H*16*16 fp32
    float* ksw = kvw + (size_t)BJ_ * H_ * 16 * 16;      // BJ*128 fp32
    const size_t zero_bytes =
        ((size_t)BJ_ * H_ * 16 * 16 + (size_t)BJ_ * d_) * sizeof(float);
    hipMemsetAsync(d_ws, 0, zero_bytes, stream);

    dim3 blk(256);
    dim3 grdK(CHK, BJ_);
    dim3 grdO(CHO, BJ_);
    hipLaunchKernelGGL(pass_kv, grdK, blk, 0, stream, x, wqkv, bqkv, kvw, ksw);
    hipLaunchKernelGGL(pass_out, grdO, blk, 0, stream, x, wqkv, bqkv, wout, bout,
                       kvw, ksw, out);
}